// Round 7
// baseline (270.738 us; speedup 1.0000x reference)
//
#include <hip/hip_runtime.h>
#include <hip/hip_bf16.h>

// DifferentiableXGB: logits = epilogue(x @ W1^T + b1)
//   split[b,n] = sum_d x[b,d]*W1[n,d] + b1[n]          (n = t*4+k, N=400)
//   S[b,t] = sum_k split[b,t,k]
//   logits[b,j] = sum_t fw[t]*S[b,t]*sum_k sigmoid(split[b,t,k])*fc_w[j,k] + fc_b[j]
//
// V15 = CO-RESIDENT small blocks: 3 blocks/CU, 3 independent barrier domains.
// R13 model: V8..V14 all pay a ~5kcy fixed stall per chunk-barrier that no
// intra-block reordering dents (V8=V11=V13~=V14); with 1 block/CU the CU
// idles through it. V14's depth-2 counted vmcnt = only +6%. m233: 2-phase
// stage+wait+barrier overhead is structural. Fix: INDEPENDENT blocks.
// V9 failed placement (160 regs x 5 waves, 2.5 waves/SIMD). V15 is airtight:
//   - 256 thr = 4 waves (2mh x 2nf); BM=64, BN=224 (N-split 2, pad 448);
//     NT=7, MT=2 -> acc 56 regs; total ~161 <= 168 (launch_bounds(256,3))
//     -> 12 waves/CU = 3/SIMD even split.
//   - LDS: A dbuf 8KB + B dbuf 28KB + P 1KB = 38KB -> 3 blocks = 114KB.
//   - plain __syncthreads per chunk (V8-proven); overlap via 3 domains.
//   - N-split => memset(out) + atomicAdd partial logits (fcb/2 per half,
//     exact); 64K atomics to distinct addresses.
//   - B staging: 14 DMA stages (16 rows = 1KB); waves 0-1: 4, waves 2-3: 3
//     (non-uniform OK: __syncthreads drains all).
//   - XOR-rotate swizzle phys_sub=(sub+(row>>1))&3 (V9-verified, 0 confl).
//   - grid 1024: bid -> mb=bid>>1, nh=bid&1 (pair shares A rows -> L3 hot).

typedef __bf16 bf16x8 __attribute__((ext_vector_type(8)));
typedef float f32x4 __attribute__((ext_vector_type(4)));

#define B_ROWS 32768
#define D_DIM  1024
#define N_COLS 400
#define NPAD   448
#define BM     64
#define BN     224
#define BK     32
#define NCHUNK 32          // 1024 / 32
#define THREADS 256        // 4 waves: mh = wave>>1, nf = wave&1
#define NTPW 7             // n-tiles (16 wide) per wave
#define MT   2             // m-tiles (16 tall) per wave (32 rows per mh)

__device__ __forceinline__ unsigned short f2bf(float f) {
    unsigned int u = __float_as_uint(f);
    u += 0x7FFFu + ((u >> 16) & 1u);   // RTNE
    return (unsigned short)(u >> 16);
}
__device__ __forceinline__ unsigned int pk2(float a, float b) {
    return (unsigned int)f2bf(a) | ((unsigned int)f2bf(b) << 16);
}
__device__ __forceinline__ uint4 cvt8u(float4 a, float4 b) {
    uint4 u;
    u.x = pk2(a.x, a.y); u.y = pk2(a.z, a.w);
    u.z = pk2(b.x, b.y); u.w = pk2(b.z, b.w);
    return u;
}
__device__ __forceinline__ bf16x8 cvt8(float4 a, float4 b) {
    return __builtin_bit_cast(bf16x8, cvt8u(a, b));
}

// W1 fp32 [400][1024] -> bf16 [448][1024] zero-padded (0.9 MB in ws)
__global__ void cvt_pad_bf16_kernel(const float* __restrict__ in,
                                    unsigned short* __restrict__ out) {
    size_t i = ((size_t)blockIdx.x * 256 + threadIdx.x) * 8;   // < 448*1024
    if (i < (size_t)N_COLS * D_DIM) {
        float4 v0 = *reinterpret_cast<const float4*>(in + i);
        float4 v1 = *reinterpret_cast<const float4*>(in + i + 4);
        *reinterpret_cast<uint4*>(out + i) = cvt8u(v0, v1);
    } else {
        uint4 z; z.x = z.y = z.z = z.w = 0u;
        *reinterpret_cast<uint4*>(out + i) = z;
    }
}

// async 16B/lane global->LDS; lds dest = wave-uniform base + lane*16 (HW)
__device__ __forceinline__ void gl_lds16(const unsigned short* g,
                                         unsigned short* l) {
    __builtin_amdgcn_global_load_lds(
        (const __attribute__((address_space(1))) unsigned int*)g,
        (__attribute__((address_space(3))) unsigned int*)l,
        16, 0, 0);
}

// ---- macro machinery: every hot value is an individually named register ----
#define FOR_N_(OP, m) OP(m,0) OP(m,1) OP(m,2) OP(m,3) OP(m,4) OP(m,5) OP(m,6)
#define FOR_MN(OP) FOR_N_(OP,0) FOR_N_(OP,1)

#define DECL_ACC(m,n) f32x4 acc##m##n = {};
#define MFMA_MN(m,n) acc##m##n = __builtin_amdgcn_mfma_f32_16x16x32_bf16( \
        afr##m, bfr##n, acc##m##n, 0, 0, 0);

// MODE 0: A fp32 (fused cvt), B bf16 padded (ws). MODE 2: both fp32, plain.
template <int MODE>
__global__ __launch_bounds__(THREADS, 3) void xgb_v15(
    const float* __restrict__ x,
    const void*  __restrict__ b_any,
    const float* __restrict__ b1,
    const float* __restrict__ fw,
    const float* __restrict__ fcw,      // [2,4]
    const float* __restrict__ fcb,      // [2]
    float* __restrict__ out)            // [B,2], pre-zeroed; atomicAdd
{
    // rows of 32 shorts (64 B), sub = 8 shorts (16 B), 4 subs/row;
    // swizzle: phys_sub = (sub + (row>>1)) & 3   (V9-verified, 0 conflicts)
    __shared__ __align__(16) unsigned short Abuf[2][BM * BK];       // 8 KB
    __shared__ __align__(16) unsigned short Bbuf[2][BN * BK];       // 28 KB
    __shared__ float Pbuf[BM * 2 * 2];                              // 1 KB

    const int tid  = threadIdx.x;
    const int wave = tid >> 6;          // 0..3
    const int lane = tid & 63;
    const int quad = lane >> 4;
    const int l15  = lane & 15;
    const int mh   = wave >> 1;         // 0..1  (m half: 32 rows)
    const int nf   = wave & 1;          // 0..1  (n half of BN: 7 tiles)
    const int mb   = blockIdx.x >> 1;
    const int nh   = blockIdx.x & 1;    // which 224-col half of NPAD
    const int row0 = mb * BM;
    const int bcol0 = nh * BN;          // W1b row offset

    FOR_MN(DECL_ACC)                    // acc00..acc16, 14 x f32x4

    if (MODE == 0) {
        const unsigned short* w1b = (const unsigned short*)b_any;

        // ---- B staging: 14 DMA stages (16 rows = 1 KB each); wave w takes
        // s = w + 4t. stage s: lane i -> buf row 16s+(i>>2), phys slot i&3;
        // fetch logical sub ((i&3) - (row>>1)) & 3 (pre-swizzled source).
#define BDECL(t) const unsigned short* bsrc##t; int bdst##t; \
        { const int s_ = wave + 4 * (t); \
          const int rb_ = s_ * 16 + (lane >> 2); \
          const int rc_ = (s_ < 14) ? rb_ : 0;        /* clamp unused */ \
          const int cc_ = ((lane & 3) - (rc_ >> 1)) & 3; \
          bsrc##t = w1b + (size_t)(bcol0 + rc_) * D_DIM + cc_ * 8; \
          bdst##t = (s_ < 14 ? s_ : 0) * 512; }       // shorts
        BDECL(0) BDECL(1) BDECL(2) BDECL(3)

#define STAGEB(kc, Bb) do { \
        gl_lds16(bsrc0 + (kc), (Bb) + bdst0); \
        gl_lds16(bsrc1 + (kc), (Bb) + bdst1); \
        gl_lds16(bsrc2 + (kc), (Bb) + bdst2); \
        if (wave < 2) gl_lds16(bsrc3 + (kc), (Bb) + bdst3); } while (0)

        // ---- A staging: 64 rows x 4 subs = 256 subs = 256 thr x 1 UNIFORM.
        const int r0a = tid >> 2, c0a = tid & 3;
        const float* asrc0 = x + (size_t)(row0 + r0a) * D_DIM + c0a * 8;
        const int adst0 = r0a * 32 + ((c0a + (r0a >> 1)) & 3) * 8;  // swizzled
        float4 areg0, areg1;

#define LOADA(kc) do { \
        areg0 = *reinterpret_cast<const float4*>(asrc0 + (kc));     \
        areg1 = *reinterpret_cast<const float4*>(asrc0 + (kc) + 4); } while (0)
#define WRITEA(Ab) do { \
        *reinterpret_cast<uint4*>((Ab) + adst0) = cvt8u(areg0, areg1); \
        } while (0)

#define LOAD_AFR(m) { const int row_ = mh * 32 + (m) * 16 + l15; \
        const int p_ = (quad + (row_ >> 1)) & 3; \
        afr##m = *reinterpret_cast<const bf16x8*>(Ab_ + row_ * 32 + p_ * 8); }
#define LOAD_BFR(n) { const int row_ = (nf * NTPW + (n)) * 16 + l15; \
        const int p_ = (quad + (row_ >> 1)) & 3; \
        bfr##n = *reinterpret_cast<const bf16x8*>(Bb_ + row_ * 32 + p_ * 8); }

        // prologue: stage chunk 0 into buffer 0
        LOADA(0);
        STAGEB(0, Bbuf[0]);
        WRITEA(Abuf[0]);

        #pragma unroll 1
        for (int c = 0; c < NCHUNK; ++c) {
            const int cur = c & 1;
            const unsigned short* Ab_ = Abuf[cur];
            const unsigned short* Bb_ = Bbuf[cur];
            __syncthreads();            // drains chunk-c staging; buf^1 free
            if (c + 1 < NCHUNK) {
                LOADA((c + 1) * BK);                 // globals fly over compute
                STAGEB((c + 1) * BK, Bbuf[1 - cur]); // dma flies over compute
            }
            {
                bf16x8 afr0, afr1;
                bf16x8 bfr0, bfr1, bfr2, bfr3, bfr4, bfr5, bfr6;
                LOAD_AFR(0) LOAD_AFR(1)
                LOAD_BFR(0) LOAD_BFR(1) LOAD_BFR(2) LOAD_BFR(3)
                LOAD_BFR(4) LOAD_BFR(5) LOAD_BFR(6)
                FOR_MN(MFMA_MN)
            }
            if (c + 1 < NCHUNK) WRITEA(Abuf[1 - cur]);  // cvt after compute
        }
    } else {
        // fallback: both fp32 direct (no ws), clamped pad cols, plain loop
        const float* af = x + (size_t)(row0 + mh * 32 + l15) * D_DIM + quad * 8;
#define PBF(n) const float* pbf##n; { \
        int r_ = bcol0 + (nf * NTPW + (n)) * 16 + l15; \
        if (r_ > N_COLS - 1) r_ = 0; \
        pbf##n = (const float*)b_any + (size_t)r_ * D_DIM + quad * 8; }
        PBF(0) PBF(1) PBF(2) PBF(3) PBF(4) PBF(5) PBF(6)
        for (int step = 0; step < NCHUNK; ++step) {
            const int off = step * BK;
            bf16x8 afr0, afr1;
            bf16x8 bfr0, bfr1, bfr2, bfr3, bfr4, bfr5, bfr6;
#define LAF2(m) afr##m = cvt8( \
            *reinterpret_cast<const float4*>(af + (size_t)(m) * 16 * D_DIM + off), \
            *reinterpret_cast<const float4*>(af + (size_t)(m) * 16 * D_DIM + off + 4));
#define LBF2(n) bfr##n = cvt8( \
            *reinterpret_cast<const float4*>(pbf##n + off), \
            *reinterpret_cast<const float4*>(pbf##n + off + 4));
            LAF2(0) LAF2(1)
            LBF2(0) LBF2(1) LBF2(2) LBF2(3) LBF2(4) LBF2(5) LBF2(6)
            FOR_MN(MFMA_MN)
        }
    }

    // ---- epilogue ----
    // C/D layout: col = l15 (within tile), row = quad*4 + reg   [m89/m91]
    const float fcw0 = fcw[l15 & 3];        // fc_w[0][k], k = col&3 (224%4==0)
    const float fcw1 = fcw[4 + (l15 & 3)];  // fc_w[1][k]

    // pad cols (>=400): bias=0, tw=0 -> exact zero contribution
#define PRE_N(n) \
    const int  col##n  = bcol0 + (nf * NTPW + (n)) * 16 + l15; \
    const bool ok##n   = (col##n < N_COLS); \
    const float bias##n = ok##n ? b1[ok##n ? col##n : 0] : 0.0f; \
    const float tw##n   = ok##n ? fw[ok##n ? (col##n >> 2) : 0] : 0.0f;
    PRE_N(0) PRE_N(1) PRE_N(2) PRE_N(3) PRE_N(4) PRE_N(5) PRE_N(6)

    // per (m,r): q = sum over n of fw[t]*sigmoid(split)*S ; then 16-lane sum.
    // k-sum S: lanes ^1,^2 (l15 bits 0-1 are k within tree).
#define EPI_TERM(m,r,n) { \
        const float split_ = acc##m##n[r] + bias##n; \
        float s_ = split_; \
        s_ += __shfl_xor(s_, 1); \
        s_ += __shfl_xor(s_, 2); \
        const float leaf_ = 1.0f / (1.0f + __expf(-split_)); \
        const float val_ = tw##n * leaf_ * s_; \
        q0 += val_ * fcw0; q1 += val_ * fcw1; }

#define EPI_ONE(m,r) { \
        float q0 = 0.f, q1 = 0.f; \
        EPI_TERM(m,r,0) EPI_TERM(m,r,1) EPI_TERM(m,r,2) EPI_TERM(m,r,3) \
        EPI_TERM(m,r,4) EPI_TERM(m,r,5) EPI_TERM(m,r,6) \
        q0 += __shfl_xor(q0, 1); q0 += __shfl_xor(q0, 2); \
        q0 += __shfl_xor(q0, 4); q0 += __shfl_xor(q0, 8); \
        q1 += __shfl_xor(q1, 1); q1 += __shfl_xor(q1, 2); \
        q1 += __shfl_xor(q1, 4); q1 += __shfl_xor(q1, 8); \
        const int row_ = mh * 32 + (m) * 16 + quad * 4 + (r);   /* 0..63 */ \
        if (l15 == 0) Pbuf[(row_ * 2 + nf) * 2 + 0] = q0; \
        if (l15 == 1) Pbuf[(row_ * 2 + nf) * 2 + 1] = q1; }

#define EPI_M(m) EPI_ONE(m,0) EPI_ONE(m,1) EPI_ONE(m,2) EPI_ONE(m,3)
    EPI_M(0) EPI_M(1)

    __syncthreads();

    if (tid < 2 * BM) {
        const int r = tid >> 1, j = tid & 1;
        // this block's partial (its 224-col half); fcb split exactly in half
        float s = 0.5f * fcb[j]
                + Pbuf[(r * 2 + 0) * 2 + j]
                + Pbuf[(r * 2 + 1) * 2 + j];
        atomicAdd(&out[(size_t)(row0 + r) * 2 + j], s);
    }
}

extern "C" void kernel_launch(void* const* d_in, const int* in_sizes, int n_in,
                              void* d_out, int out_size, void* d_ws, size_t ws_size,
                              hipStream_t stream) {
    const float* x   = (const float*)d_in[0];
    const float* W1  = (const float*)d_in[1];
    const float* b1  = (const float*)d_in[2];
    const float* fw  = (const float*)d_in[3];
    const float* fcw = (const float*)d_in[4];
    const float* fcb = (const float*)d_in[5];
    float* out = (float*)d_out;

    // out is accumulated atomically by 2 N-half blocks per row -> zero first
    hipMemsetAsync(out, 0, (size_t)B_ROWS * 2 * sizeof(float), stream);

    const size_t pad_elems = (size_t)NPAD * D_DIM;    // 458,752
    if (ws_size >= pad_elems * sizeof(unsigned short)) {
        unsigned short* w1b = (unsigned short*)d_ws;
        cvt_pad_bf16_kernel<<<(int)(pad_elems / 2048), 256, 0, stream>>>(W1, w1b);
        xgb_v15<0><<<(B_ROWS / BM) * 2, THREADS, 0, stream>>>(
            x, (const void*)w1b, b1, fw, fcw, fcb, out);
    } else {
        xgb_v15<2><<<(B_ROWS / BM) * 2, THREADS, 0, stream>>>(
            x, (const void*)W1, b1, fw, fcw, fcb, out);
    }
}

// Round 9
// 268.342 us; speedup vs baseline: 1.0089x; 1.0089x over previous
//
#include <hip/hip_runtime.h>
#include <hip/hip_bf16.h>

// DifferentiableXGB: logits = epilogue(x @ W1^T + b1)
//   split[b,n] = sum_d x[b,d]*W1[n,d] + b1[n]          (n = t*4+k, N=400)
//   S[b,t] = sum_k split[b,t,k]
//   logits[b,j] = sum_t fw[t]*S[b,t]*sum_k sigmoid(split[b,t,k])*fc_w[j,k] + fc_b[j]
//
// V17 = V16 (producer/consumer, 4-deep LDS ring) with the flag-count bug
// fixed. R15 post-mortem: V16's NaN was atomicAdd executed by ALL 64 LANES
// -> one producer wave bumped prodf by 64; consumers (waiting >=4) released
// after 1/4 of the staging landed -> read unstaged LDS -> NaN. The vmcnt
// ledger itself re-traces clean. Fixes:
//   1. lane==0 guard on prodf/consf atomicAdd (each wave contributes 1).
//   2. asm volatile("" ::: "memory") after each poll loop: slot ds_reads
//      have no data-dep on the flag -> pin IR ordering (plus sched_barrier).
// Structure (unchanged):
//   - 512 thr: waves 0-3 PRODUCE, waves 4-7 CONSUME. BM=64, BK=32,
//     NCHUNK=32, NSLOT=4. Grid 512 (m-split only: A read ONCE).
//   - ring slot: A 64x32 bf16 (4KB) + B 448x32 bf16 (28KB); 4 slots=128KB.
//   - producer/chunk/lane: 2 A-loads (fp32->cvt->1 ds_write_b128) +
//     7 B global_load_lds; 2 chunks ahead; counted ledger: steady 18
//     outstanding; vmcnt(16)->A(c) retired, write; vmcnt(9)->batch c
//     retired; lgkmcnt(0); flag. Tail c=31: 7/0.
//   - consumer/chunk: poll prodf[slot]>=4*(c/4+1), 11 ds_read_b128 +
//     28 MFMA (MT=4,NT=7, acc=112), lgkmcnt(0), flag consf.
//   - monotonic counters, no resets; NO barrier in the loop.
//   - swizzle phys_sub=(sub+(row>>1))&3; DMA dest linear, source
//     pre-swizzled (both-sides rule).
//   - NPAD=448; pad cols: B=0 and tw=bias=0 in epilogue -> exact zeros.

typedef __bf16 bf16x8 __attribute__((ext_vector_type(8)));
typedef float f32x4 __attribute__((ext_vector_type(4)));

#define B_ROWS 32768
#define D_DIM  1024
#define N_COLS 400
#define NPAD   448
#define BM     64
#define BK     32
#define NCHUNK 32          // 1024 / 32
#define NSLOT  4
#define THREADS 512        // 4 producer waves + 4 consumer waves
#define NTPW 7             // n-tiles per consumer wave (4*7*16 = 448)
#define MT   4             // m-tiles per consumer wave (64 rows)

__device__ __forceinline__ unsigned short f2bf(float f) {
    unsigned int u = __float_as_uint(f);
    u += 0x7FFFu + ((u >> 16) & 1u);   // RTNE
    return (unsigned short)(u >> 16);
}
__device__ __forceinline__ unsigned int pk2(float a, float b) {
    return (unsigned int)f2bf(a) | ((unsigned int)f2bf(b) << 16);
}
__device__ __forceinline__ uint4 cvt8u(float4 a, float4 b) {
    uint4 u;
    u.x = pk2(a.x, a.y); u.y = pk2(a.z, a.w);
    u.z = pk2(b.x, b.y); u.w = pk2(b.z, b.w);
    return u;
}
__device__ __forceinline__ bf16x8 cvt8(float4 a, float4 b) {
    return __builtin_bit_cast(bf16x8, cvt8u(a, b));
}

// W1 fp32 [400][1024] -> bf16 [448][1024] zero-padded (0.9 MB in ws)
__global__ void cvt_pad_bf16_kernel(const float* __restrict__ in,
                                    unsigned short* __restrict__ out) {
    size_t i = ((size_t)blockIdx.x * 256 + threadIdx.x) * 8;   // < 448*1024
    if (i < (size_t)N_COLS * D_DIM) {
        float4 v0 = *reinterpret_cast<const float4*>(in + i);
        float4 v1 = *reinterpret_cast<const float4*>(in + i + 4);
        *reinterpret_cast<uint4*>(out + i) = cvt8u(v0, v1);
    } else {
        uint4 z; z.x = z.y = z.z = z.w = 0u;
        *reinterpret_cast<uint4*>(out + i) = z;
    }
}

// async 16B/lane global->LDS; lds dest = wave-uniform base + lane*16 (HW)
__device__ __forceinline__ void gl_lds16(const unsigned short* g,
                                         unsigned short* l) {
    __builtin_amdgcn_global_load_lds(
        (const __attribute__((address_space(1))) unsigned int*)g,
        (__attribute__((address_space(3))) unsigned int*)l,
        16, 0, 0);
}

// ---- macro machinery: every hot value is an individually named register ----
#define FOR_N_(OP, m) OP(m,0) OP(m,1) OP(m,2) OP(m,3) OP(m,4) OP(m,5) OP(m,6)
#define FOR_MN(OP) FOR_N_(OP,0) FOR_N_(OP,1) FOR_N_(OP,2) FOR_N_(OP,3)

#define DECL_ACC(m,n) f32x4 acc##m##n = {};
#define MFMA_MN(m,n) acc##m##n = __builtin_amdgcn_mfma_f32_16x16x32_bf16( \
        afr##m, bfr##n, acc##m##n, 0, 0, 0);

// MODE 0: producer/consumer (ws). MODE 2: both fp32 direct (insurance).
template <int MODE>
__global__ __launch_bounds__(THREADS, 2) void xgb_v17(
    const float* __restrict__ x,
    const void*  __restrict__ b_any,
    const float* __restrict__ b1,
    const float* __restrict__ fw,
    const float* __restrict__ fcw,      // [2,4]
    const float* __restrict__ fcb,      // [2]
    float* __restrict__ out)            // [B,2]
{
    // rows of 32 shorts (64 B), sub = 8 shorts (16 B), 4 subs/row;
    // swizzle: phys_sub = (sub + (row>>1)) & 3
    __shared__ __align__(16) unsigned short Aslot[NSLOT][BM * BK];   // 16 KB
    __shared__ __align__(16) unsigned short Bslot[NSLOT][NPAD * BK]; // 112 KB
    __shared__ float Pbuf[BM * 4 * 2];                               // 2 KB
    __shared__ int prodf[NSLOT];
    __shared__ int consf[NSLOT];

    const int tid  = threadIdx.x;
    const int wave = tid >> 6;          // 0..7
    const int lane = tid & 63;
    const int quad = lane >> 4;
    const int l15  = lane & 15;
    const int row0 = blockIdx.x * BM;

    if (tid < NSLOT) { prodf[tid] = 0; consf[tid] = 0; }
    __syncthreads();

    if (MODE == 0 && wave < 4) {
        // ================= PRODUCERS (waves 0..3) =================
        const unsigned short* w1b = (const unsigned short*)b_any;

        // A: 64 rows x 4 subs = 256 subs, one per producer lane (tid 0..255)
        const int r0a = tid >> 2, c0a = tid & 3;
        const float* asrc = x + (size_t)(row0 + r0a) * D_DIM + c0a * 8;
        const int adst = r0a * 32 + ((c0a + (r0a >> 1)) & 3) * 8;  // swizzled

        // B: 28 stages (16 rows = 1 KB each), 7 per wave. stage s_: lane i
        // -> row 16s_+(i>>2), phys slot i&3; fetch logical sub
        // ((i&3)-(row>>1))&3 (pre-swizzled source); dest linear.
#define BDECL(t) const unsigned short* bsrc##t; int bdst##t; \
        { const int s_ = wave + 4 * (t); \
          const int rb_ = s_ * 16 + (lane >> 2); \
          const int cc_ = ((lane & 3) - (rb_ >> 1)) & 3; \
          bsrc##t = w1b + (size_t)rb_ * D_DIM + cc_ * 8; \
          bdst##t = s_ * 512; }
        BDECL(0) BDECL(1) BDECL(2) BDECL(3) BDECL(4) BDECL(5) BDECL(6)

        float4 aXlo, aXhi, aYlo, aYhi;

#define PISSUE(S, c) do { \
        unsigned short* Bb_ = Bslot[(c) & 3]; \
        const int kc_ = (c) * BK; \
        a##S##lo = *reinterpret_cast<const float4*>(asrc + kc_); \
        a##S##hi = *reinterpret_cast<const float4*>(asrc + kc_ + 4); \
        __builtin_amdgcn_sched_barrier(0); \
        gl_lds16(bsrc0 + kc_, Bb_ + bdst0); \
        gl_lds16(bsrc1 + kc_, Bb_ + bdst1); \
        gl_lds16(bsrc2 + kc_, Bb_ + bdst2); \
        gl_lds16(bsrc3 + kc_, Bb_ + bdst3); \
        gl_lds16(bsrc4 + kc_, Bb_ + bdst4); \
        gl_lds16(bsrc5 + kc_, Bb_ + bdst5); \
        gl_lds16(bsrc6 + kc_, Bb_ + bdst6); \
        __builtin_amdgcn_sched_barrier(0); \
        } while (0)

#define PWRITE(S, c) do { \
        unsigned short* Ab_ = Aslot[(c) & 3]; \
        *reinterpret_cast<uint4*>(Ab_ + adst) = cvt8u(a##S##lo, a##S##hi); \
        } while (0)

        PISSUE(X, 0);                   // batch 0: 2 A + 7 DMA
        PISSUE(Y, 1);                   // batch 1 (slots 0,1: free at start)

        #pragma unroll 1
        for (int c = 0; c < NCHUNK; ++c) {
            // steady state at loop top: batches c and c+1 in flight (18 ops)
            if (c < NCHUNK - 1) asm volatile("s_waitcnt vmcnt(16)" ::: "memory");
            else                asm volatile("s_waitcnt vmcnt(7)"  ::: "memory");
            if (c & 1) PWRITE(Y, c); else PWRITE(X, c);      // cvt + ds_write
            if (c < NCHUNK - 1) asm volatile("s_waitcnt vmcnt(9)" ::: "memory");
            else                asm volatile("s_waitcnt vmcnt(0)" ::: "memory");
            asm volatile("s_waitcnt lgkmcnt(0)" ::: "memory");
            __builtin_amdgcn_sched_barrier(0);
            if (lane == 0) atomicAdd(&prodf[c & 3], 1);  // chunk c staged (1/wave)
            if (c + 2 < NCHUNK) {
                const int cn = c + 2;
                const int want = 4 * (cn >> 2); // consumers done with cn-4
                if (want > 0) {
                    while (((volatile int*)consf)[cn & 3] < want)
                        __builtin_amdgcn_s_sleep(1);
                }
                asm volatile("" ::: "memory");  // pin DMA issue after poll
                __builtin_amdgcn_sched_barrier(0);
                if (cn & 1) PISSUE(Y, cn); else PISSUE(X, cn);
            }
        }
    } else if (wave >= 4) {
        // ================= CONSUMERS (waves 4..7) =================
        const int cw = wave - 4;        // n-quarter 0..3
        FOR_MN(DECL_ACC)                // acc00..acc36, 28 x f32x4

#define LOAD_AFR(m) { const int row_ = (m) * 16 + l15; \
        const int p_ = (quad + (row_ >> 1)) & 3; \
        afr##m = *reinterpret_cast<const bf16x8*>(Ab_ + row_ * 32 + p_ * 8); }
#define LOAD_BFR(n) { const int row_ = (cw * NTPW + (n)) * 16 + l15; \
        const int p_ = (quad + (row_ >> 1)) & 3; \
        bfr##n = *reinterpret_cast<const bf16x8*>(Bb_ + row_ * 32 + p_ * 8); }

        if (MODE == 0) {
            #pragma unroll 1
            for (int c = 0; c < NCHUNK; ++c) {
                const int s_ = c & 3;
                const int want = 4 * ((c >> 2) + 1);
                while (((volatile int*)prodf)[s_] < want)
                    __builtin_amdgcn_s_sleep(1);
                asm volatile("" ::: "memory");  // pin slot reads after poll
                __builtin_amdgcn_sched_barrier(0);
                const unsigned short* Ab_ = Aslot[s_];
                const unsigned short* Bb_ = Bslot[s_];
                bf16x8 afr0, afr1, afr2, afr3;
                bf16x8 bfr0, bfr1, bfr2, bfr3, bfr4, bfr5, bfr6;
                LOAD_AFR(0) LOAD_AFR(1) LOAD_AFR(2) LOAD_AFR(3)
                LOAD_BFR(0) LOAD_BFR(1) LOAD_BFR(2) LOAD_BFR(3)
                LOAD_BFR(4) LOAD_BFR(5) LOAD_BFR(6)
                FOR_MN(MFMA_MN)
                asm volatile("s_waitcnt lgkmcnt(0)" ::: "memory");
                __builtin_amdgcn_sched_barrier(0);
                if (lane == 0) atomicAdd(&consf[s_], 1); // slot reusable (1/wave)
            }
        } else {
            // fallback: both fp32 direct (no ws), clamped pad cols
            const float* af = x + (size_t)(row0 + l15) * D_DIM + quad * 8;
#define PBF(n) const float* pbf##n; { \
            int r_ = (cw * NTPW + (n)) * 16 + l15; \
            if (r_ > N_COLS - 1) r_ = 0; \
            pbf##n = (const float*)b_any + (size_t)r_ * D_DIM + quad * 8; }
            PBF(0) PBF(1) PBF(2) PBF(3) PBF(4) PBF(5) PBF(6)
            for (int step = 0; step < NCHUNK; ++step) {
                const int off = step * BK;
                bf16x8 afr0, afr1, afr2, afr3;
                bf16x8 bfr0, bfr1, bfr2, bfr3, bfr4, bfr5, bfr6;
#define LAF2(m) afr##m = cvt8( \
                *reinterpret_cast<const float4*>(af + (size_t)(m) * 16 * D_DIM + off), \
                *reinterpret_cast<const float4*>(af + (size_t)(m) * 16 * D_DIM + off + 4));
#define LBF2(n) bfr##n = cvt8( \
                *reinterpret_cast<const float4*>(pbf##n + off), \
                *reinterpret_cast<const float4*>(pbf##n + off + 4));
                LAF2(0) LAF2(1) LAF2(2) LAF2(3)
                LBF2(0) LBF2(1) LBF2(2) LBF2(3) LBF2(4) LBF2(5) LBF2(6)
                FOR_MN(MFMA_MN)
            }
        }

        // ---- per-consumer epilogue into Pbuf ----
        // C/D layout: col = l15 (within tile), row = quad*4 + reg  [m89/m91]
        const float fcw0 = fcw[l15 & 3];        // fc_w[0][k], k = col&3
        const float fcw1 = fcw[4 + (l15 & 3)];  // fc_w[1][k]

        // pad cols (>=400): bias=0, tw=0 -> exact zero contribution
#define PRE_N(n) \
        const int  col##n  = (cw * NTPW + (n)) * 16 + l15; \
        const bool ok##n   = (col##n < N_COLS); \
        const float bias##n = ok##n ? b1[ok##n ? col##n : 0] : 0.0f; \
        const float tw##n   = ok##n ? fw[ok##n ? (col##n >> 2) : 0] : 0.0f;
        PRE_N(0) PRE_N(1) PRE_N(2) PRE_N(3) PRE_N(4) PRE_N(5) PRE_N(6)

#define EPI_TERM(m,r,n) { \
        const float split_ = acc##m##n[r] + bias##n; \
        float s_ = split_; \
        s_ += __shfl_xor(s_, 1); \
        s_ += __shfl_xor(s_, 2); \
        const float leaf_ = 1.0f / (1.0f + __expf(-split_)); \
        const float val_ = tw##n * leaf_ * s_; \
        q0 += val_ * fcw0; q1 += val_ * fcw1; }

#define EPI_ONE(m,r) { \
        float q0 = 0.f, q1 = 0.f; \
        EPI_TERM(m,r,0) EPI_TERM(m,r,1) EPI_TERM(m,r,2) EPI_TERM(m,r,3) \
        EPI_TERM(m,r,4) EPI_TERM(m,r,5) EPI_TERM(m,r,6) \
        q0 += __shfl_xor(q0, 1); q0 += __shfl_xor(q0, 2); \
        q0 += __shfl_xor(q0, 4); q0 += __shfl_xor(q0, 8); \
        q1 += __shfl_xor(q1, 1); q1 += __shfl_xor(q1, 2); \
        q1 += __shfl_xor(q1, 4); q1 += __shfl_xor(q1, 8); \
        const int row_ = (m) * 16 + quad * 4 + (r);           /* 0..63 */ \
        if (l15 == 0) Pbuf[(row_ * 4 + cw) * 2 + 0] = q0; \
        if (l15 == 1) Pbuf[(row_ * 4 + cw) * 2 + 1] = q1; }

#define EPI_M(m) EPI_ONE(m,0) EPI_ONE(m,1) EPI_ONE(m,2) EPI_ONE(m,3)
        EPI_M(0) EPI_M(1) EPI_M(2) EPI_M(3)
    }

    __syncthreads();

    if (tid < 2 * BM) {
        const int r = tid >> 1, j = tid & 1;
        float s = fcb[j];
        #pragma unroll
        for (int w = 0; w < 4; ++w)
            s += Pbuf[(r * 4 + w) * 2 + j];
        out[(size_t)(row0 + r) * 2 + j] = s;
    }
}

extern "C" void kernel_launch(void* const* d_in, const int* in_sizes, int n_in,
                              void* d_out, int out_size, void* d_ws, size_t ws_size,
                              hipStream_t stream) {
    const float* x   = (const float*)d_in[0];
    const float* W1  = (const float*)d_in[1];
    const float* b1  = (const float*)d_in[2];
    const float* fw  = (const float*)d_in[3];
    const float* fcw = (const float*)d_in[4];
    const float* fcb = (const float*)d_in[5];
    float* out = (float*)d_out;

    const size_t pad_elems = (size_t)NPAD * D_DIM;    // 458,752
    if (ws_size >= pad_elems * sizeof(unsigned short)) {
        unsigned short* w1b = (unsigned short*)d_ws;
        cvt_pad_bf16_kernel<<<(int)(pad_elems / 2048), 256, 0, stream>>>(W1, w1b);
        xgb_v17<0><<<B_ROWS / BM, THREADS, 0, stream>>>(
            x, (const void*)w1b, b1, fw, fcw, fcb, out);
    } else {
        xgb_v17<2><<<B_ROWS / BM, THREADS, 0, stream>>>(
            x, (const void*)W1, b1, fw, fcw, fcb, out);
    }
}

// Round 10
// 240.501 us; speedup vs baseline: 1.1257x; 1.1158x over previous
//
#include <hip/hip_runtime.h>
#include <hip/hip_bf16.h>

// DifferentiableXGB: logits = epilogue(x @ W1^T + b1)
//   split[b,n] = sum_d x[b,d]*W1[n,d] + b1[n]          (n = t*4+k, N=400)
//   S[b,t] = sum_k split[b,t,k]
//   logits[b,j] = sum_t fw[t]*S[b,t]*sum_k sigmoid(split[b,t,k])*fc_w[j,k] + fc_b[j]
//
// V18 = V14's all-waves lockstep structure with the ring deepened to 4
// slots (3-chunk staging runway) under per-wave counted vmcnt.
// R16 post-mortem: V17 (producer/consumer) correct but 157us — 4 MFMA waves
// = half throughput; specialization abandoned. V14 (83us) analysis: per
// chunk 12.5kcy vs component sum ~6kcy -> pieces serialized. V14's B-DMAs
// had only ONE chunk of cover (issued at c for c+1); A depth-2 marginal.
// V18: batch(c) = {4 B-DMA (waves 0-6) + 2 A-loads (all)} issued 3 chunks
// early into a 4-slot ring; at top of chunk c only batch(c) is retired
// (vmcnt(12); wave7 A-only: vmcnt(4)); batches c+1,c+2 stay in flight
// ACROSS the barrier. Loop unrolled x4 -> slot/regset indices compile-time
// (rule #20). Steady state: waits pre-satisfied, chunk ~= compute+barrier.
//   - BM=128, BK=32, NCHUNK=32, NSLOT=4; slot = A 8KB + B 28KB; LDS 148KB.
//   - 512 thr = 8 waves (2mh x 4nf); NT=7 (NPAD=448), MT=4; acc 112.
//   - A: 512 subs = 1/thread (2 float4 loads, cvt, 1 ds_write_b128).
//   - B: 28 DMA stages (16 rows = 1KB), 4 per wave for waves 0..6.
//   - swizzle phys_sub=(sub+(row>>1))&3 (V9/V15-verified); DMA dest linear,
//     source pre-swizzled (both-sides rule).
//   - pad cols >=400: B=0, tw=bias=0 in epilogue -> exact zero contribution.
//   - launch_bounds(512,2); ~200 of 256 regs incl 112 AGPR -> no spills.

typedef __bf16 bf16x8 __attribute__((ext_vector_type(8)));
typedef float f32x4 __attribute__((ext_vector_type(4)));

#define B_ROWS 32768
#define D_DIM  1024
#define N_COLS 400
#define NPAD   448
#define BM     128
#define BK     32
#define NCHUNK 32          // 1024 / 32
#define NSLOT  4
#define THREADS 512        // 8 waves: mh = wave>>2, nf = wave&3
#define NTPW 7             // n-tiles (16 wide) per wave (4*7 = 28 = 448)
#define MT   4             // m-tiles (16 tall) per wave (64 rows per mh)

__device__ __forceinline__ unsigned short f2bf(float f) {
    unsigned int u = __float_as_uint(f);
    u += 0x7FFFu + ((u >> 16) & 1u);   // RTNE
    return (unsigned short)(u >> 16);
}
__device__ __forceinline__ unsigned int pk2(float a, float b) {
    return (unsigned int)f2bf(a) | ((unsigned int)f2bf(b) << 16);
}
__device__ __forceinline__ uint4 cvt8u(float4 a, float4 b) {
    uint4 u;
    u.x = pk2(a.x, a.y); u.y = pk2(a.z, a.w);
    u.z = pk2(b.x, b.y); u.w = pk2(b.z, b.w);
    return u;
}
__device__ __forceinline__ bf16x8 cvt8(float4 a, float4 b) {
    return __builtin_bit_cast(bf16x8, cvt8u(a, b));
}

// W1 fp32 [400][1024] -> bf16 [448][1024] zero-padded (0.9 MB in ws)
__global__ void cvt_pad_bf16_kernel(const float* __restrict__ in,
                                    unsigned short* __restrict__ out) {
    size_t i = ((size_t)blockIdx.x * 256 + threadIdx.x) * 8;   // < 448*1024
    if (i < (size_t)N_COLS * D_DIM) {
        float4 v0 = *reinterpret_cast<const float4*>(in + i);
        float4 v1 = *reinterpret_cast<const float4*>(in + i + 4);
        *reinterpret_cast<uint4*>(out + i) = cvt8u(v0, v1);
    } else {
        uint4 z; z.x = z.y = z.z = z.w = 0u;
        *reinterpret_cast<uint4*>(out + i) = z;
    }
}

// async 16B/lane global->LDS; lds dest = wave-uniform base + lane*16 (HW)
__device__ __forceinline__ void gl_lds16(const unsigned short* g,
                                         unsigned short* l) {
    __builtin_amdgcn_global_load_lds(
        (const __attribute__((address_space(1))) unsigned int*)g,
        (__attribute__((address_space(3))) unsigned int*)l,
        16, 0, 0);
}

// ---- macro machinery: every hot value is an individually named register ----
#define FOR_N_(OP, m) OP(m,0) OP(m,1) OP(m,2) OP(m,3) OP(m,4) OP(m,5) OP(m,6)
#define FOR_MN(OP) FOR_N_(OP,0) FOR_N_(OP,1) FOR_N_(OP,2) FOR_N_(OP,3)

#define DECL_ACC(m,n) f32x4 acc##m##n = {};
#define MFMA_MN(m,n) acc##m##n = __builtin_amdgcn_mfma_f32_16x16x32_bf16( \
        afr##m, bfr##n, acc##m##n, 0, 0, 0);

// MODE 0: ring pipeline (ws). MODE 2: both fp32 direct (insurance).
template <int MODE>
__global__ __launch_bounds__(THREADS, 2) void xgb_v18(
    const float* __restrict__ x,
    const void*  __restrict__ b_any,
    const float* __restrict__ b1,
    const float* __restrict__ fw,
    const float* __restrict__ fcw,      // [2,4]
    const float* __restrict__ fcb,      // [2]
    float* __restrict__ out)            // [B,2]
{
    // rows of 32 shorts (64 B), sub = 8 shorts (16 B), 4 subs/row;
    // swizzle: phys_sub = (sub + (row>>1)) & 3
    __shared__ __align__(16) unsigned short Aslot[NSLOT][BM * BK];   // 32 KB
    __shared__ __align__(16) unsigned short Bslot[NSLOT][NPAD * BK]; // 112 KB
    __shared__ float Pbuf[BM * 4 * 2];                               // 4 KB

    const int tid  = threadIdx.x;
    const int wave = tid >> 6;          // 0..7
    const int lane = tid & 63;
    const int quad = lane >> 4;
    const int l15  = lane & 15;
    const int mh   = wave >> 2;         // 0..1  (m half: 64 rows)
    const int nf   = wave & 3;          // 0..3  (n quarter: 7 tiles)
    const int row0 = blockIdx.x * BM;

    FOR_MN(DECL_ACC)                    // acc00..acc36, 28 x f32x4

    if (MODE == 0) {
        const unsigned short* w1b = (const unsigned short*)b_any;

        // ---- B staging: 28 DMA stages (16 rows = 1 KB each); waves 0..6
        // take s = wave + 7t (t=0..3). stage s: lane i -> row 16s+(i>>2),
        // phys slot i&3; fetch logical sub ((i&3)-(row>>1))&3 (pre-swizzled
        // source); dest linear.
#define BDECL(t) const unsigned short* bsrc##t; int bdst##t; \
        { const int s_ = wave + 7 * (t); \
          const int rb_ = s_ * 16 + (lane >> 2); \
          const int cc_ = ((lane & 3) - (rb_ >> 1)) & 3; \
          bsrc##t = w1b + (size_t)rb_ * D_DIM + cc_ * 8; \
          bdst##t = s_ * 512; }
        BDECL(0) BDECL(1) BDECL(2) BDECL(3)

#define STAGEB(kc, Bb) do { if (wave < 7) { \
        gl_lds16(bsrc0 + (kc), (Bb) + bdst0); \
        gl_lds16(bsrc1 + (kc), (Bb) + bdst1); \
        gl_lds16(bsrc2 + (kc), (Bb) + bdst2); \
        gl_lds16(bsrc3 + (kc), (Bb) + bdst3); } } while (0)

        // ---- A staging: 128 rows x 4 subs = 512 subs = 1 per thread.
        const int r0a = tid >> 2, c0a = tid & 3;
        const float* asrc = x + (size_t)(row0 + r0a) * D_DIM + c0a * 8;
        const int adst = r0a * 32 + ((c0a + (r0a >> 1)) & 3) * 8;   // swizzled
        // 4 named fp32 reg sets, one per ring slot (compile-time indexed)
        float4 aR0a, aR0b, aR1a, aR1b, aR2a, aR2b, aR3a, aR3b;

#define LOADA(S, kc) do { \
        aR##S##a = *reinterpret_cast<const float4*>(asrc + (kc));     \
        aR##S##b = *reinterpret_cast<const float4*>(asrc + (kc) + 4); } while (0)
#define WRITEA(S, Ab) do { \
        *reinterpret_cast<uint4*>((Ab) + adst) = cvt8u(aR##S##a, aR##S##b); \
        } while (0)

#define LOAD_AFR(m) { const int row_ = mh * 64 + (m) * 16 + l15; \
        const int p_ = (quad + (row_ >> 1)) & 3; \
        afr##m = *reinterpret_cast<const bf16x8*>(Ab_ + row_ * 32 + p_ * 8); }
#define LOAD_BFR(n) { const int row_ = (nf * NTPW + (n)) * 16 + l15; \
        const int p_ = (quad + (row_ >> 1)) & 3; \
        bfr##n = *reinterpret_cast<const bf16x8*>(Bb_ + row_ * 32 + p_ * 8); }

#define COMPUTE(PH) do { \
        const unsigned short* Ab_ = Aslot[PH]; \
        const unsigned short* Bb_ = Bslot[PH]; \
        bf16x8 afr0, afr1, afr2, afr3; \
        bf16x8 bfr0, bfr1, bfr2, bfr3, bfr4, bfr5, bfr6; \
        LOAD_AFR(0) LOAD_AFR(1) LOAD_AFR(2) LOAD_AFR(3) \
        LOAD_BFR(0) LOAD_BFR(1) LOAD_BFR(2) LOAD_BFR(3) \
        LOAD_BFR(4) LOAD_BFR(5) LOAD_BFR(6) \
        FOR_MN(MFMA_MN) \
        } while (0)

        // per-wave counted wait retiring exactly batch(c): outstanding
        // after wait = remaining batches (c+1, c+2 clamped to <=31).
#define VMWAIT(c_) do { \
        if ((c_) <= NCHUNK - 3) { \
            if (wave < 7) asm volatile("s_waitcnt vmcnt(12)" ::: "memory"); \
            else          asm volatile("s_waitcnt vmcnt(4)"  ::: "memory"); \
        } else if ((c_) == NCHUNK - 2) { \
            if (wave < 7) asm volatile("s_waitcnt vmcnt(6)" ::: "memory"); \
            else          asm volatile("s_waitcnt vmcnt(2)" ::: "memory"); \
        } else { \
            asm volatile("s_waitcnt vmcnt(0)" ::: "memory"); \
        } \
        __builtin_amdgcn_sched_barrier(0); \
        } while (0)

        // PH = c&3 (slot+regset of chunk c), PH3 = (PH+3)&3 (batch c+3)
#define CHUNK_BODY(PH, PH3, cc) do { \
        const int c_ = (cc) + (PH); \
        VMWAIT(c_); \
        WRITEA(PH, Aslot[PH]); \
        asm volatile("s_waitcnt lgkmcnt(0)" ::: "memory"); \
        __builtin_amdgcn_s_barrier(); \
        __builtin_amdgcn_sched_barrier(0); \
        if (c_ + 3 < NCHUNK) { \
            const int kc3_ = (c_ + 3) * BK; \
            STAGEB(kc3_, Bslot[PH3]); \
            LOADA(PH3, kc3_); \
        } \
        __builtin_amdgcn_sched_barrier(0); \
        COMPUTE(PH); \
        } while (0)

        // ---- prologue: batches 0,1,2 issued in batch order (pinned) ----
        STAGEB(0, Bslot[0]);  LOADA(0, 0);
        __builtin_amdgcn_sched_barrier(0);
        STAGEB(BK, Bslot[1]); LOADA(1, BK);
        __builtin_amdgcn_sched_barrier(0);
        STAGEB(2 * BK, Bslot[2]); LOADA(2, 2 * BK);
        __builtin_amdgcn_sched_barrier(0);

        #pragma unroll 1
        for (int cc = 0; cc < NCHUNK; cc += 4) {
            CHUNK_BODY(0, 3, cc);
            CHUNK_BODY(1, 0, cc);
            CHUNK_BODY(2, 1, cc);
            CHUNK_BODY(3, 2, cc);
        }
    } else {
        // fallback: both fp32 direct (no ws), clamped pad cols, plain loop
        const float* af = x + (size_t)(row0 + mh * 64 + l15) * D_DIM + quad * 8;
#define PBF(n) const float* pbf##n; { \
        int r_ = (nf * NTPW + (n)) * 16 + l15; if (r_ > N_COLS - 1) r_ = 0; \
        pbf##n = (const float*)b_any + (size_t)r_ * D_DIM + quad * 8; }
        PBF(0) PBF(1) PBF(2) PBF(3) PBF(4) PBF(5) PBF(6)
        for (int step = 0; step < 32; ++step) {
            const int off = step * 32;
            bf16x8 afr0, afr1, afr2, afr3;
            bf16x8 bfr0, bfr1, bfr2, bfr3, bfr4, bfr5, bfr6;
#define LAF2(m) afr##m = cvt8( \
            *reinterpret_cast<const float4*>(af + (size_t)(m) * 16 * D_DIM + off), \
            *reinterpret_cast<const float4*>(af + (size_t)(m) * 16 * D_DIM + off + 4));
#define LBF2(n) bfr##n = cvt8( \
            *reinterpret_cast<const float4*>(pbf##n + off), \
            *reinterpret_cast<const float4*>(pbf##n + off + 4));
            LAF2(0) LAF2(1) LAF2(2) LAF2(3)
            LBF2(0) LBF2(1) LBF2(2) LBF2(3) LBF2(4) LBF2(5) LBF2(6)
            FOR_MN(MFMA_MN)
        }
    }

    // ---- epilogue ----
    // C/D layout: col = l15 (within tile), row = quad*4 + reg   [m89/m91]
    const float fcw0 = fcw[l15 & 3];        // fc_w[0][k], k = col&3
    const float fcw1 = fcw[4 + (l15 & 3)];  // fc_w[1][k]

    // pad cols (>=400): bias=0, tw=0 -> exact zero contribution
#define PRE_N(n) \
    const int  col##n  = (nf * NTPW + (n)) * 16 + l15; \
    const bool ok##n   = (col##n < N_COLS); \
    const float bias##n = ok##n ? b1[ok##n ? col##n : 0] : 0.0f; \
    const float tw##n   = ok##n ? fw[ok##n ? (col##n >> 2) : 0] : 0.0f;
    PRE_N(0) PRE_N(1) PRE_N(2) PRE_N(3) PRE_N(4) PRE_N(5) PRE_N(6)

    // per (m,r): q = sum over n of fw[t]*sigmoid(split)*S ; then 16-lane sum.
    // k-sum S: lanes ^1,^2 (l15 bits 0-1 are k within tree).
#define EPI_TERM(m,r,n) { \
        const float split_ = acc##m##n[r] + bias##n; \
        float s_ = split_; \
        s_ += __shfl_xor(s_, 1); \
        s_ += __shfl_xor(s_, 2); \
        const float leaf_ = 1.0f / (1.0f + __expf(-split_)); \
        const float val_ = tw##n * leaf_ * s_; \
        q0 += val_ * fcw0; q1 += val_ * fcw1; }

#define EPI_ONE(m,r) { \
        float q0 = 0.f, q1 = 0.f; \
        EPI_TERM(m,r,0) EPI_TERM(m,r,1) EPI_TERM(m,r,2) EPI_TERM(m,r,3) \
        EPI_TERM(m,r,4) EPI_TERM(m,r,5) EPI_TERM(m,r,6) \
        q0 += __shfl_xor(q0, 1); q0 += __shfl_xor(q0, 2); \
        q0 += __shfl_xor(q0, 4); q0 += __shfl_xor(q0, 8); \
        q1 += __shfl_xor(q1, 1); q1 += __shfl_xor(q1, 2); \
        q1 += __shfl_xor(q1, 4); q1 += __shfl_xor(q1, 8); \
        const int row_ = mh * 64 + (m) * 16 + quad * 4 + (r);   /* 0..127 */ \
        if (l15 == 0) Pbuf[(row_ * 4 + nf) * 2 + 0] = q0; \
        if (l15 == 1) Pbuf[(row_ * 4 + nf) * 2 + 1] = q1; }

#define EPI_M(m) EPI_ONE(m,0) EPI_ONE(m,1) EPI_ONE(m,2) EPI_ONE(m,3)
    EPI_M(0) EPI_M(1) EPI_M(2) EPI_M(3)

    __syncthreads();

    if (tid < 2 * BM) {
        const int r = tid >> 1, j = tid & 1;
        float s = fcb[j];
        #pragma unroll
        for (int w = 0; w < 4; ++w)
            s += Pbuf[(r * 4 + w) * 2 + j];
        out[(size_t)(row0 + r) * 2 + j] = s;
    }
}

extern "C" void kernel_launch(void* const* d_in, const int* in_sizes, int n_in,
                              void* d_out, int out_size, void* d_ws, size_t ws_size,
                              hipStream_t stream) {
    const float* x   = (const float*)d_in[0];
    const float* W1  = (const float*)d_in[1];
    const float* b1  = (const float*)d_in[2];
    const float* fw  = (const float*)d_in[3];
    const float* fcw = (const float*)d_in[4];
    const float* fcb = (const float*)d_in[5];
    float* out = (float*)d_out;

    const size_t pad_elems = (size_t)NPAD * D_DIM;    // 458,752
    if (ws_size >= pad_elems * sizeof(unsigned short)) {
        unsigned short* w1b = (unsigned short*)d_ws;
        cvt_pad_bf16_kernel<<<(int)(pad_elems / 2048), 256, 0, stream>>>(W1, w1b);
        xgb_v18<0><<<B_ROWS / BM, THREADS, 0, stream>>>(
            x, (const void*)w1b, b1, fw, fcw, fcb, out);
    } else {
        xgb_v18<2><<<B_ROWS / BM, THREADS, 0, stream>>>(
            x, (const void*)W1, b1, fw, fcw, fcb, out);
    }
}